// Round 1
// baseline (740.448 us; speedup 1.0000x reference)
//
#include <hip/hip_runtime.h>
#include <math.h>

// FourierCrossAttention, MI355X fp32 baseline.
// B=32 H=8 E=64 M=64 O=64 L=1024. v/mask/index inputs unused (indices are arange(64)).
//
// ws layout (floats), total 12,845,056 floats = 51.4 MB:
#define OFF_TABQC 0u        // [t][m] cos(2pi m t/1024)   65536
#define OFF_TABQS 65536u    // [t][m] sin
#define OFF_TABIC 131072u   // [m][t] cos (iDFT staging layout)
#define OFF_TABIS 196608u   // [m][t] sin
#define OFF_WTR   262144u   // wT[h][x][e][o]  2097152
#define OFF_WTI   2359296u
#define OFF_XQR   4456448u  // Xq [b][h][e][m] 1048576
#define OFF_XQI   5505024u
#define OFF_XKR   6553600u
#define OFF_XKI   7602176u
#define OFF_UR    8650752u  // u  [h][x][b][e] 1048576
#define OFF_UI    9699328u
#define OFF_YR    10747904u // xqkvw [h][m][b][o] 1048576
#define OFF_YI    11796480u

#define PI_F 3.14159265358979323846f

// ---------------- twiddle tables (exact angle reduction: (m*t) mod 1024) ----
__global__ void k_tables(float* __restrict__ ws) {
    int idx = blockIdx.x * 256 + threadIdx.x;   // 65536 entries
    int t = idx >> 6, m = idx & 63;
    int r = (m * t) & 1023;
    float ang = (float)r * (2.0f * PI_F / 1024.0f);
    float s, c;
    sincosf(ang, &s, &c);
    ws[OFF_TABQC + t * 64 + m] = c;
    ws[OFF_TABQS + t * 64 + m] = s;
    ws[OFF_TABIC + m * 1024 + t] = c;
    ws[OFF_TABIS + m * 1024 + t] = s;
}

// ---------------- transpose weights [h][e][o][x] -> [h][x][e][o] ------------
__global__ __launch_bounds__(256) void k_wt(const float* __restrict__ wr,
                                            const float* __restrict__ wi,
                                            float* __restrict__ ws) {
    __shared__ float tile[64 * 65];
    int he = blockIdx.x;            // h*64+e
    int h = he >> 6, e = he & 63;
    const float* srcs[2] = { wr + (size_t)he * 4096, wi + (size_t)he * 4096 };
    float* dsts[2] = { ws + OFF_WTR, ws + OFF_WTI };
    for (int p = 0; p < 2; ++p) {
        __syncthreads();
        {
            int x = threadIdx.x & 63, orow = threadIdx.x >> 6;
            for (int i = 0; i < 16; ++i) {
                int o = orow * 16 + i;
                tile[o * 65 + x] = srcs[p][o * 64 + x];
            }
        }
        __syncthreads();
        {
            int o = threadIdx.x & 63, xrow = threadIdx.x >> 6;
            for (int i = 0; i < 16; ++i) {
                int x = xrow * 16 + i;
                dsts[p][(((size_t)h * 64 + x) * 64 + e) * 64 + o] = tile[o * 65 + x];
            }
        }
    }
}

// ---------------- DFT of q and k: 64 modes of 1024-pt rfft ------------------
// grid 512: src*256 + b*8 + h.  lane = mode m; 4 waves split t; LDS reduce.
__global__ __launch_bounds__(256, 2) void k_dft(const float* __restrict__ q,
                                                const float* __restrict__ kk,
                                                float* __restrict__ ws) {
    int blk = blockIdx.x;
    int src = blk >> 8;
    int bh = blk & 255;
    int b = bh >> 3, h = bh & 7;
    const float* A = src ? kk : q;
    float* outR = ws + (src ? OFF_XKR : OFF_XQR) + (size_t)bh * 4096;
    float* outI = ws + (src ? OFF_XKI : OFF_XQI) + (size_t)bh * 4096;
    const float* tc = ws + OFF_TABQC;
    const float* tsn = ws + OFF_TABQS;
    int lane = threadIdx.x & 63;
    int wv = threadIdx.x >> 6;

    float accR[64], accI[64];
#pragma unroll
    for (int e = 0; e < 64; ++e) { accR[e] = 0.f; accI[e] = 0.f; }

    int t0 = wv * 256;
    for (int t = t0; t < t0 + 256; ++t) {
        float c = tc[t * 64 + lane];
        float s = tsn[t * 64 + lane];
        const float4* a4 = (const float4*)(A + (((size_t)b * 1024 + t) * 8 + h) * 64);
#pragma unroll
        for (int j = 0; j < 16; ++j) {
            float4 a = a4[j];
            accR[4 * j + 0] += a.x * c; accI[4 * j + 0] -= a.x * s;
            accR[4 * j + 1] += a.y * c; accI[4 * j + 1] -= a.y * s;
            accR[4 * j + 2] += a.z * c; accI[4 * j + 2] -= a.z * s;
            accR[4 * j + 3] += a.w * c; accI[4 * j + 3] -= a.w * s;
        }
    }

    __shared__ float redR[4096], redI[4096];
    if (wv == 0) {
#pragma unroll
        for (int e = 0; e < 64; ++e) { redR[e * 64 + lane] = accR[e]; redI[e * 64 + lane] = accI[e]; }
    }
    __syncthreads();
    for (int w = 1; w < 4; ++w) {
        if (wv == w) {
#pragma unroll
            for (int e = 0; e < 64; ++e) { redR[e * 64 + lane] += accR[e]; redI[e * 64 + lane] += accI[e]; }
        }
        __syncthreads();
    }
    for (int i = threadIdx.x; i < 4096; i += 256) {
        outR[i] = redR[i];
        outI[i] = redI[i];
    }
}

// ---------------- S = Xq^T Xk, tanh, u = S~ Xk^T  (per (b,h)) ---------------
__global__ __launch_bounds__(256, 1) void k_attn(float* __restrict__ ws) {
    __shared__ float bufA[8192];   // Xq planes [e][m]; later S~ planes [y][x]
    __shared__ float bufB[8192];   // Xk planes [e][m]; later KT [m][e]
    int bh = blockIdx.x;
    int tid = threadIdx.x;
    const float* XqR = ws + OFF_XQR + (size_t)bh * 4096;
    const float* XqI = ws + OFF_XQI + (size_t)bh * 4096;
    const float* XkR = ws + OFF_XKR + (size_t)bh * 4096;
    const float* XkI = ws + OFF_XKI + (size_t)bh * 4096;
    for (int i = tid; i < 4096; i += 256) {
        bufA[i] = XqR[i]; bufA[4096 + i] = XqI[i];
        bufB[i] = XkR[i]; bufB[4096 + i] = XkI[i];
    }
    __syncthreads();

    // phase 2: S[x][y] = sum_e Xq[e][x]*Xk[e][y] (complex, no conj)
    int x4 = tid & 15, y4 = tid >> 4;
    int x0 = x4 * 4, y0 = y4 * 4;
    float Sr[4][4], Si[4][4];
#pragma unroll
    for (int a = 0; a < 4; ++a)
#pragma unroll
        for (int bidx = 0; bidx < 4; ++bidx) { Sr[a][bidx] = 0.f; Si[a][bidx] = 0.f; }
#pragma unroll 8
    for (int e = 0; e < 64; ++e) {
        float4 qr = *(const float4*)&bufA[e * 64 + x0];
        float4 qi = *(const float4*)&bufA[4096 + e * 64 + x0];
        float4 kr = *(const float4*)&bufB[e * 64 + y0];
        float4 ki = *(const float4*)&bufB[4096 + e * 64 + y0];
        float qra[4] = { qr.x, qr.y, qr.z, qr.w };
        float qia[4] = { qi.x, qi.y, qi.z, qi.w };
        float kra[4] = { kr.x, kr.y, kr.z, kr.w };
        float kia[4] = { ki.x, ki.y, ki.z, ki.w };
#pragma unroll
        for (int xi = 0; xi < 4; ++xi)
#pragma unroll
            for (int yi = 0; yi < 4; ++yi) {
                Sr[xi][yi] += qra[xi] * kra[yi] - qia[xi] * kia[yi];
                Si[xi][yi] += qra[xi] * kia[yi] + qia[xi] * kra[yi];
            }
    }
#pragma unroll
    for (int xi = 0; xi < 4; ++xi)
#pragma unroll
        for (int yi = 0; yi < 4; ++yi) {
            Sr[xi][yi] = tanhf(Sr[xi][yi]);
            Si[xi][yi] = tanhf(Si[xi][yi]);
        }
    __syncthreads();   // all reads of bufA/bufB in phase 2 done

    // phase 3a: store S~ transposed as [y][x] into bufA
#pragma unroll
    for (int xi = 0; xi < 4; ++xi)
#pragma unroll
        for (int yi = 0; yi < 4; ++yi) {
            bufA[(y0 + yi) * 64 + x0 + xi] = Sr[xi][yi];
            bufA[4096 + (y0 + yi) * 64 + x0 + xi] = Si[xi][yi];
        }
    // phase 3b: transpose bufB in place: Xk[e][m] -> KT[m][e]
    float tR[16], tI[16];
#pragma unroll
    for (int j = 0; j < 16; ++j) {
        int idx = tid + 256 * j;
        tR[j] = bufB[idx]; tI[j] = bufB[4096 + idx];
    }
    __syncthreads();
#pragma unroll
    for (int j = 0; j < 16; ++j) {
        int idx = tid + 256 * j;
        int e = idx >> 6, m = idx & 63;
        bufB[m * 64 + e] = tR[j];
        bufB[4096 + m * 64 + e] = tI[j];
    }
    __syncthreads();

    // phase 4: u[e][x] = sum_y S~stored[y][x] * KT[y][e]   (complex)
    int e4 = tid & 15, xb4 = tid >> 4;
    int e0 = e4 * 4, xb0 = xb4 * 4;
    float uR[4][4], uI[4][4];   // [ei][xi]
#pragma unroll
    for (int a = 0; a < 4; ++a)
#pragma unroll
        for (int bidx = 0; bidx < 4; ++bidx) { uR[a][bidx] = 0.f; uI[a][bidx] = 0.f; }
#pragma unroll 8
    for (int y = 0; y < 64; ++y) {
        float4 sr = *(const float4*)&bufA[y * 64 + xb0];
        float4 si = *(const float4*)&bufA[4096 + y * 64 + xb0];
        float4 kr = *(const float4*)&bufB[y * 64 + e0];
        float4 ki = *(const float4*)&bufB[4096 + y * 64 + e0];
        float sra[4] = { sr.x, sr.y, sr.z, sr.w };
        float sia[4] = { si.x, si.y, si.z, si.w };
        float kra[4] = { kr.x, kr.y, kr.z, kr.w };
        float kia[4] = { ki.x, ki.y, ki.z, ki.w };
#pragma unroll
        for (int ei = 0; ei < 4; ++ei)
#pragma unroll
            for (int xi = 0; xi < 4; ++xi) {
                uR[ei][xi] += sra[xi] * kra[ei] - sia[xi] * kia[ei];
                uI[ei][xi] += sra[xi] * kia[ei] + sia[xi] * kra[ei];
            }
    }
    int b = bh >> 3, h = bh & 7;
    float* uRp = ws + OFF_UR;
    float* uIp = ws + OFF_UI;
#pragma unroll
    for (int xi = 0; xi < 4; ++xi) {
        size_t base = (((size_t)h * 64 + (xb0 + xi)) * 32 + b) * 64 + e0;
        float4 vr = { uR[0][xi], uR[1][xi], uR[2][xi], uR[3][xi] };
        float4 vi = { uI[0][xi], uI[1][xi], uI[2][xi], uI[3][xi] };
        *(float4*)&uRp[base] = vr;
        *(float4*)&uIp[base] = vi;
    }
}

// ---------------- xqkvw[b][o] = sum_e u[b][e] * w[e][o]  per (h,x) ----------
__global__ __launch_bounds__(256, 2) void k_uw(float* __restrict__ ws) {
    __shared__ float su[2 * 2176];   // [p][b][e] stride 68 (bank-spread)
    __shared__ float sw[2 * 4096];   // [p][e][o]
    int hx = blockIdx.x;
    int tid = threadIdx.x;
    const float* uRp = ws + OFF_UR + (size_t)hx * 2048;
    const float* uIp = ws + OFF_UI + (size_t)hx * 2048;
    const float* wRp = ws + OFF_WTR + (size_t)hx * 4096;
    const float* wIp = ws + OFF_WTI + (size_t)hx * 4096;
    for (int i = tid; i < 2048; i += 256) {
        int b = i >> 6, e = i & 63;
        su[b * 68 + e] = uRp[i];
        su[2176 + b * 68 + e] = uIp[i];
    }
    for (int i = tid; i < 4096; i += 256) {
        sw[i] = wRp[i];
        sw[4096 + i] = wIp[i];
    }
    __syncthreads();
    int o16 = tid & 15, b8 = tid >> 4;
    int o0 = o16 * 4, b0 = b8 * 2;
    float aR[2][4], aI[2][4];
#pragma unroll
    for (int bi = 0; bi < 2; ++bi)
#pragma unroll
        for (int oi = 0; oi < 4; ++oi) { aR[bi][oi] = 0.f; aI[bi][oi] = 0.f; }
#pragma unroll 8
    for (int e = 0; e < 64; ++e) {
        float u0r = su[(b0 + 0) * 68 + e], u0i = su[2176 + (b0 + 0) * 68 + e];
        float u1r = su[(b0 + 1) * 68 + e], u1i = su[2176 + (b0 + 1) * 68 + e];
        float4 wr = *(const float4*)&sw[e * 64 + o0];
        float4 wi = *(const float4*)&sw[4096 + e * 64 + o0];
        float wra[4] = { wr.x, wr.y, wr.z, wr.w };
        float wia[4] = { wi.x, wi.y, wi.z, wi.w };
#pragma unroll
        for (int oi = 0; oi < 4; ++oi) {
            aR[0][oi] += u0r * wra[oi] - u0i * wia[oi];
            aI[0][oi] += u0r * wia[oi] + u0i * wra[oi];
            aR[1][oi] += u1r * wra[oi] - u1i * wia[oi];
            aI[1][oi] += u1r * wia[oi] + u1i * wra[oi];
        }
    }
    float* YRp = ws + OFF_YR + (size_t)hx * 2048;
    float* YIp = ws + OFF_YI + (size_t)hx * 2048;
#pragma unroll
    for (int bi = 0; bi < 2; ++bi) {
        float4 vr = { aR[bi][0], aR[bi][1], aR[bi][2], aR[bi][3] };
        float4 vi = { aI[bi][0], aI[bi][1], aI[bi][2], aI[bi][3] };
        *(float4*)&YRp[(b0 + bi) * 64 + o0] = vr;
        *(float4*)&YIp[(b0 + bi) * 64 + o0] = vi;
    }
}

// ---------------- iDFT: out[b][h][o][t] = s*sum_m a_m(XR cos - XI sin) ------
__global__ __launch_bounds__(256, 2) void k_idft(const float* __restrict__ ws,
                                                 float* __restrict__ out) {
    __shared__ float sc[8192];   // scaled coeffs [p][m][o]
    __shared__ float sb[8192];   // basis tile   [p][m][tl]
    int bh = blockIdx.x;
    int b = bh >> 3, h = bh & 7;
    int tid = threadIdx.x;
    const float S0 = 3.7252902984619140625e-09f;   // 1/2^28 = 1/(1024*512*512)
    const float* YRp = ws + OFF_YR;
    const float* YIp = ws + OFF_YI;
    for (int i = tid; i < 4096; i += 256) {
        int m = i >> 6, o = i & 63;
        size_t src = ((size_t)h * 64 + m) * 2048 + (size_t)b * 64 + o;
        float sca = (m == 0 ? 1.f : 2.f) * S0;
        sc[i] = YRp[src] * sca;
        sc[4096 + i] = YIp[src] * sca;
    }
    const float* tic = ws + OFF_TABIC;
    const float* tis = ws + OFF_TABIS;
    for (int tc = 0; tc < 16; ++tc) {
        __syncthreads();   // protects sb reuse (and sc on first iter)
        for (int i = tid; i < 4096; i += 256) {
            int m = i >> 6, tl = i & 63;
            sb[i] = tic[m * 1024 + tc * 64 + tl];
            sb[4096 + i] = tis[m * 1024 + tc * 64 + tl];
        }
        __syncthreads();
        int t4 = tid & 15, o4 = tid >> 4;
        int tl0 = t4 * 4, o0 = o4 * 4;
        float acc[4][4];   // [oi][ti]
#pragma unroll
        for (int a = 0; a < 4; ++a)
#pragma unroll
            for (int c = 0; c < 4; ++c) acc[a][c] = 0.f;
#pragma unroll 8
        for (int m = 0; m < 64; ++m) {
            float4 cr = *(const float4*)&sc[m * 64 + o0];
            float4 ci = *(const float4*)&sc[4096 + m * 64 + o0];
            float4 bc = *(const float4*)&sb[m * 64 + tl0];
            float4 bs = *(const float4*)&sb[4096 + m * 64 + tl0];
            float cra[4] = { cr.x, cr.y, cr.z, cr.w };
            float cia[4] = { ci.x, ci.y, ci.z, ci.w };
            float bca[4] = { bc.x, bc.y, bc.z, bc.w };
            float bsa[4] = { bs.x, bs.y, bs.z, bs.w };
#pragma unroll
            for (int oi = 0; oi < 4; ++oi)
#pragma unroll
                for (int ti = 0; ti < 4; ++ti)
                    acc[oi][ti] += cra[oi] * bca[ti] - cia[oi] * bsa[ti];
        }
#pragma unroll
        for (int oi = 0; oi < 4; ++oi) {
            float4 v = { acc[oi][0], acc[oi][1], acc[oi][2], acc[oi][3] };
            *(float4*)&out[(((size_t)b * 8 + h) * 64 + o0 + oi) * 1024 + tc * 64 + tl0] = v;
        }
    }
}

extern "C" void kernel_launch(void* const* d_in, const int* in_sizes, int n_in,
                              void* d_out, int out_size, void* d_ws, size_t ws_size,
                              hipStream_t stream) {
    const float* q = (const float*)d_in[0];
    const float* k = (const float*)d_in[1];
    // d_in[2]=v, d_in[3]=mask unused by reference; d_in[6]/[7] indices == arange(64)
    const float* wr = (const float*)d_in[4];
    const float* wi = (const float*)d_in[5];
    float* out = (float*)d_out;
    float* ws = (float*)d_ws;   // needs 51.4 MB

    k_tables<<<256, 256, 0, stream>>>(ws);
    k_wt<<<512, 256, 0, stream>>>(wr, wi, ws);
    k_dft<<<512, 256, 0, stream>>>(q, k, ws);
    k_attn<<<256, 256, 0, stream>>>(ws);
    k_uw<<<512, 256, 0, stream>>>(ws);
    k_idft<<<256, 256, 0, stream>>>(ws, out);
}

// Round 2
// 341.119 us; speedup vs baseline: 2.1706x; 2.1706x over previous
//
#include <hip/hip_runtime.h>
#include <math.h>

// FourierCrossAttention, MI355X. Round 2: DFT + iDFT via split-bf16 MFMA (3-pass).
// B=32 H=8 E=64 M=64 O=64 L=1024.
//
// ws layout:
//   bytes [0, 1MB): bf16 twiddle tables in MFMA B-fragment layout
//     BDH ushort[131072] @ 0       DFT  B[k][n] hi   (k=1024, n=128: cos||-sin)
//     BDL ushort[131072] @ 256KB   DFT  lo
//     BIH ushort[131072] @ 512KB   iDFT B[kap][t] hi (kap=128: cos;-sin, t=1024)
//     BIL ushort[131072] @ 768KB   iDFT lo
//   floats from index 262144 (=1MB): unchanged from round 1.
#define OFF_WTR   262144u   // wT[h][x][e][o]  2097152
#define OFF_WTI   2359296u
#define OFF_XQR   4456448u  // Xq [b][h][e][m] 1048576
#define OFF_XQI   5505024u
#define OFF_XKR   6553600u
#define OFF_XKI   7602176u
#define OFF_UR    8650752u  // u  [h][x][b][e] 1048576
#define OFF_UI    9699328u
#define OFF_YR    10747904u // xqkvw [h][m][b][o] 1048576
#define OFF_YI    11796480u

#define PI_F 3.14159265358979323846f

typedef __attribute__((ext_vector_type(8))) short bf16x8;
typedef __attribute__((ext_vector_type(4))) float f32x4;

__device__ inline unsigned short f2bf(float f) {
    unsigned u = __float_as_uint(f);
    unsigned r = u + 0x7FFFu + ((u >> 16) & 1u);
    return (unsigned short)(r >> 16);
}
__device__ inline float bf2f(unsigned short h) {
    return __uint_as_float(((unsigned)h) << 16);
}
__device__ inline void make_hilo8(const float* s, bf16x8& h, bf16x8& l) {
#pragma unroll
    for (int j = 0; j < 8; ++j) {
        unsigned short hb = f2bf(s[j]);
        h[j] = (short)hb;
        l[j] = (short)f2bf(s[j] - bf2f(hb));
    }
}
__device__ inline float twval(int m, int t, bool neg_sin) {
    int r = (m * t) & 1023;
    float ang = (float)r * (2.0f * PI_F / 1024.0f);
    float s, c;
    sincosf(ang, &s, &c);
    return neg_sin ? -s : c;
}

// ---------------- twiddle tables in MFMA B-fragment layout, split hi/lo -----
__global__ void k_tables(unsigned short* __restrict__ tab) {
    int idx = blockIdx.x * 256 + threadIdx.x;   // 131072 entries each table
    // DFT table: frag (kt in 0..31, nt in 0..7), entry ((kt*8+nt)*64+lane)*8+j
    {
        int j = idx & 7, lane = (idx >> 3) & 63, nt = (idx >> 9) & 7, kt = idx >> 12;
        int k = kt * 32 + ((lane >> 4) << 3) + j;       // t index (K dim)
        int n = nt * 16 + (lane & 15);                  // col in [0,128)
        float v = twval(n & 63, k, n >= 64);
        unsigned short hb = f2bf(v);
        tab[idx] = hb;
        tab[131072 + idx] = f2bf(v - bf2f(hb));
    }
    // iDFT table: frag (nt in 0..63, ks in 0..3), entry ((nt*4+ks)*64+lane)*8+j
    {
        int j = idx & 7, lane = (idx >> 3) & 63, ks = (idx >> 9) & 3, nt = idx >> 11;
        int kap = ks * 32 + ((lane >> 4) << 3) + j;     // kappa in [0,128)
        int t = nt * 16 + (lane & 15);
        float v = twval(kap & 63, t, kap >= 64);
        unsigned short hb = f2bf(v);
        tab[262144 + idx] = hb;
        tab[393216 + idx] = f2bf(v - bf2f(hb));
    }
}

// ---------------- transpose weights [h][e][o][x] -> [h][x][e][o] ------------
__global__ __launch_bounds__(256) void k_wt(const float* __restrict__ wr,
                                            const float* __restrict__ wi,
                                            float* __restrict__ ws) {
    __shared__ float tile[64 * 65];
    int he = blockIdx.x;            // h*64+e
    int h = he >> 6, e = he & 63;
    const float* srcs[2] = { wr + (size_t)he * 4096, wi + (size_t)he * 4096 };
    float* dsts[2] = { ws + OFF_WTR, ws + OFF_WTI };
    for (int p = 0; p < 2; ++p) {
        __syncthreads();
        {
            int x = threadIdx.x & 63, orow = threadIdx.x >> 6;
            for (int i = 0; i < 16; ++i) {
                int o = orow * 16 + i;
                tile[o * 65 + x] = srcs[p][o * 64 + x];
            }
        }
        __syncthreads();
        {
            int o = threadIdx.x & 63, xrow = threadIdx.x >> 6;
            for (int i = 0; i < 16; ++i) {
                int x = xrow * 16 + i;
                dsts[p][(((size_t)h * 64 + x) * 64 + e) * 64 + o] = tile[o * 65 + x];
            }
        }
    }
}

// ---------------- DFT via MFMA: X[e][cos|-sin cols] = x[e][t] * W[t][n] -----
// grid 512: src*256 + b*8 + h. 4 waves: 2x2 split (e-half x n-half).
__global__ __launch_bounds__(256, 2) void k_dft(const float* __restrict__ q,
                                                const float* __restrict__ kk,
                                                float* __restrict__ ws) {
    int blk = blockIdx.x;
    int src = blk >> 8;
    int bh = blk & 255;
    int b = bh >> 3, h = bh & 7;
    const float* A = src ? kk : q;
    const unsigned short* BDH = (const unsigned short*)ws;
    const unsigned short* BDL = BDH + 131072;

    __shared__ float Ald[64 * 68];   // [e][t_local], row stride 68 (2-way free)

    int tid = threadIdx.x;
    int lane = tid & 63, wv = tid >> 6;
    int mhalf = wv & 1, nhalf = wv >> 1;

    f32x4 acc[2][4];
#pragma unroll
    for (int a = 0; a < 2; ++a)
#pragma unroll
        for (int c = 0; c < 4; ++c) acc[a][c] = (f32x4){0.f, 0.f, 0.f, 0.f};

    for (int kc = 0; kc < 16; ++kc) {   // stages of 64 t
        __syncthreads();
        int t0 = kc * 64;
        int e0 = (tid & 15) * 4;
#pragma unroll
        for (int it = 0; it < 4; ++it) {
            int tl = it * 16 + (tid >> 4);
            float4 a = *(const float4*)(A + (((size_t)b * 1024 + t0 + tl) * 8 + h) * 64 + e0);
            Ald[(e0 + 0) * 68 + tl] = a.x;
            Ald[(e0 + 1) * 68 + tl] = a.y;
            Ald[(e0 + 2) * 68 + tl] = a.z;
            Ald[(e0 + 3) * 68 + tl] = a.w;
        }
        __syncthreads();
#pragma unroll
        for (int k2 = 0; k2 < 2; ++k2) {   // 2 MFMA k-steps (32 t each)
            int ktile = kc * 2 + k2;
            bf16x8 ah[2], al[2];
#pragma unroll
            for (int mt = 0; mt < 2; ++mt) {
                int e = mhalf * 32 + mt * 16 + (lane & 15);
                int tt = k2 * 32 + (lane >> 4) * 8;
                float4 p0 = *(const float4*)&Ald[e * 68 + tt];
                float4 p1 = *(const float4*)&Ald[e * 68 + tt + 4];
                float f[8] = { p0.x, p0.y, p0.z, p0.w, p1.x, p1.y, p1.z, p1.w };
                make_hilo8(f, ah[mt], al[mt]);
            }
#pragma unroll
            for (int ntl = 0; ntl < 4; ++ntl) {
                int nt = nhalf * 4 + ntl;
                size_t off = (((size_t)ktile * 8 + nt) * 64 + lane) * 8;
                bf16x8 bh = *(const bf16x8*)(BDH + off);
                bf16x8 bl = *(const bf16x8*)(BDL + off);
#pragma unroll
                for (int mt = 0; mt < 2; ++mt) {
                    acc[mt][ntl] = __builtin_amdgcn_mfma_f32_16x16x32_bf16(ah[mt], bh, acc[mt][ntl], 0, 0, 0);
                    acc[mt][ntl] = __builtin_amdgcn_mfma_f32_16x16x32_bf16(ah[mt], bl, acc[mt][ntl], 0, 0, 0);
                    acc[mt][ntl] = __builtin_amdgcn_mfma_f32_16x16x32_bf16(al[mt], bh, acc[mt][ntl], 0, 0, 0);
                }
            }
        }
    }

    // epilogue: C col=lane&15, row=(lane>>4)*4+reg
    float* outR = ws + (src ? OFF_XKR : OFF_XQR) + (size_t)bh * 4096;
    float* outI = ws + (src ? OFF_XKI : OFF_XQI) + (size_t)bh * 4096;
#pragma unroll
    for (int mt = 0; mt < 2; ++mt)
#pragma unroll
        for (int ntl = 0; ntl < 4; ++ntl) {
            int n = (nhalf * 4 + ntl) * 16 + (lane & 15);
            float* dst = (n < 64) ? (outR + (n & 63)) : (outI + (n & 63));
            int erow0 = mhalf * 32 + mt * 16 + (lane >> 4) * 4;
#pragma unroll
            for (int r = 0; r < 4; ++r)
                dst[(erow0 + r) * 64] = acc[mt][ntl][r];
        }
}

// ---------------- S = Xq^T Xk, tanh, u = S~ Xk^T  (per (b,h)) ---------------
__global__ __launch_bounds__(256, 1) void k_attn(float* __restrict__ ws) {
    __shared__ float bufA[8192];   // Xq planes [e][m]; later S~ planes [y][x]
    __shared__ float bufB[8192];   // Xk planes [e][m]; later KT [m][e]
    int bh = blockIdx.x;
    int tid = threadIdx.x;
    const float* XqR = ws + OFF_XQR + (size_t)bh * 4096;
    const float* XqI = ws + OFF_XQI + (size_t)bh * 4096;
    const float* XkR = ws + OFF_XKR + (size_t)bh * 4096;
    const float* XkI = ws + OFF_XKI + (size_t)bh * 4096;
    for (int i = tid; i < 4096; i += 256) {
        bufA[i] = XqR[i]; bufA[4096 + i] = XqI[i];
        bufB[i] = XkR[i]; bufB[4096 + i] = XkI[i];
    }
    __syncthreads();

    // phase 2: S[x][y] = sum_e Xq[e][x]*Xk[e][y] (complex, no conj)
    int x4 = tid & 15, y4 = tid >> 4;
    int x0 = x4 * 4, y0 = y4 * 4;
    float Sr[4][4], Si[4][4];
#pragma unroll
    for (int a = 0; a < 4; ++a)
#pragma unroll
        for (int bidx = 0; bidx < 4; ++bidx) { Sr[a][bidx] = 0.f; Si[a][bidx] = 0.f; }
#pragma unroll 8
    for (int e = 0; e < 64; ++e) {
        float4 qr = *(const float4*)&bufA[e * 64 + x0];
        float4 qi = *(const float4*)&bufA[4096 + e * 64 + x0];
        float4 kr = *(const float4*)&bufB[e * 64 + y0];
        float4 ki = *(const float4*)&bufB[4096 + e * 64 + y0];
        float qra[4] = { qr.x, qr.y, qr.z, qr.w };
        float qia[4] = { qi.x, qi.y, qi.z, qi.w };
        float kra[4] = { kr.x, kr.y, kr.z, kr.w };
        float kia[4] = { ki.x, ki.y, ki.z, ki.w };
#pragma unroll
        for (int xi = 0; xi < 4; ++xi)
#pragma unroll
            for (int yi = 0; yi < 4; ++yi) {
                Sr[xi][yi] += qra[xi] * kra[yi] - qia[xi] * kia[yi];
                Si[xi][yi] += qra[xi] * kia[yi] + qia[xi] * kra[yi];
            }
    }
#pragma unroll
    for (int xi = 0; xi < 4; ++xi)
#pragma unroll
        for (int yi = 0; yi < 4; ++yi) {
            Sr[xi][yi] = tanhf(Sr[xi][yi]);
            Si[xi][yi] = tanhf(Si[xi][yi]);
        }
    __syncthreads();   // all reads of bufA/bufB in phase 2 done

    // phase 3a: store S~ transposed as [y][x] into bufA
#pragma unroll
    for (int xi = 0; xi < 4; ++xi)
#pragma unroll
        for (int yi = 0; yi < 4; ++yi) {
            bufA[(y0 + yi) * 64 + x0 + xi] = Sr[xi][yi];
            bufA[4096 + (y0 + yi) * 64 + x0 + xi] = Si[xi][yi];
        }
    // phase 3b: transpose bufB in place: Xk[e][m] -> KT[m][e]
    float tR[16], tI[16];
#pragma unroll
    for (int j = 0; j < 16; ++j) {
        int idx = tid + 256 * j;
        tR[j] = bufB[idx]; tI[j] = bufB[4096 + idx];
    }
    __syncthreads();
#pragma unroll
    for (int j = 0; j < 16; ++j) {
        int idx = tid + 256 * j;
        int e = idx >> 6, m = idx & 63;
        bufB[m * 64 + e] = tR[j];
        bufB[4096 + m * 64 + e] = tI[j];
    }
    __syncthreads();

    // phase 4: u[e][x] = sum_y S~stored[y][x] * KT[y][e]   (complex)
    int e4 = tid & 15, xb4 = tid >> 4;
    int e0 = e4 * 4, xb0 = xb4 * 4;
    float uR[4][4], uI[4][4];   // [ei][xi]
#pragma unroll
    for (int a = 0; a < 4; ++a)
#pragma unroll
        for (int bidx = 0; bidx < 4; ++bidx) { uR[a][bidx] = 0.f; uI[a][bidx] = 0.f; }
#pragma unroll 8
    for (int y = 0; y < 64; ++y) {
        float4 sr = *(const float4*)&bufA[y * 64 + xb0];
        float4 si = *(const float4*)&bufA[4096 + y * 64 + xb0];
        float4 kr = *(const float4*)&bufB[y * 64 + e0];
        float4 ki = *(const float4*)&bufB[4096 + y * 64 + e0];
        float sra[4] = { sr.x, sr.y, sr.z, sr.w };
        float sia[4] = { si.x, si.y, si.z, si.w };
        float kra[4] = { kr.x, kr.y, kr.z, kr.w };
        float kia[4] = { ki.x, ki.y, ki.z, ki.w };
#pragma unroll
        for (int ei = 0; ei < 4; ++ei)
#pragma unroll
            for (int xi = 0; xi < 4; ++xi) {
                uR[ei][xi] += sra[xi] * kra[ei] - sia[xi] * kia[ei];
                uI[ei][xi] += sra[xi] * kia[ei] + sia[xi] * kra[ei];
            }
    }
    int b = bh >> 3, h = bh & 7;
    float* uRp = ws + OFF_UR;
    float* uIp = ws + OFF_UI;
#pragma unroll
    for (int xi = 0; xi < 4; ++xi) {
        size_t base = (((size_t)h * 64 + (xb0 + xi)) * 32 + b) * 64 + e0;
        float4 vr = { uR[0][xi], uR[1][xi], uR[2][xi], uR[3][xi] };
        float4 vi = { uI[0][xi], uI[1][xi], uI[2][xi], uI[3][xi] };
        *(float4*)&uRp[base] = vr;
        *(float4*)&uIp[base] = vi;
    }
}

// ---------------- xqkvw[b][o] = sum_e u[b][e] * w[e][o]  per (h,x) ----------
__global__ __launch_bounds__(256, 2) void k_uw(float* __restrict__ ws) {
    __shared__ float su[2 * 2176];   // [p][b][e] stride 68 (bank-spread)
    __shared__ float sw[2 * 4096];   // [p][e][o]
    int hx = blockIdx.x;
    int tid = threadIdx.x;
    const float* uRp = ws + OFF_UR + (size_t)hx * 2048;
    const float* uIp = ws + OFF_UI + (size_t)hx * 2048;
    const float* wRp = ws + OFF_WTR + (size_t)hx * 4096;
    const float* wIp = ws + OFF_WTI + (size_t)hx * 4096;
    for (int i = tid; i < 2048; i += 256) {
        int b = i >> 6, e = i & 63;
        su[b * 68 + e] = uRp[i];
        su[2176 + b * 68 + e] = uIp[i];
    }
    for (int i = tid; i < 4096; i += 256) {
        sw[i] = wRp[i];
        sw[4096 + i] = wIp[i];
    }
    __syncthreads();
    int o16 = tid & 15, b8 = tid >> 4;
    int o0 = o16 * 4, b0 = b8 * 2;
    float aR[2][4], aI[2][4];
#pragma unroll
    for (int bi = 0; bi < 2; ++bi)
#pragma unroll
        for (int oi = 0; oi < 4; ++oi) { aR[bi][oi] = 0.f; aI[bi][oi] = 0.f; }
#pragma unroll 8
    for (int e = 0; e < 64; ++e) {
        float u0r = su[(b0 + 0) * 68 + e], u0i = su[2176 + (b0 + 0) * 68 + e];
        float u1r = su[(b0 + 1) * 68 + e], u1i = su[2176 + (b0 + 1) * 68 + e];
        float4 wr = *(const float4*)&sw[e * 64 + o0];
        float4 wi = *(const float4*)&sw[4096 + e * 64 + o0];
        float wra[4] = { wr.x, wr.y, wr.z, wr.w };
        float wia[4] = { wi.x, wi.y, wi.z, wi.w };
#pragma unroll
        for (int oi = 0; oi < 4; ++oi) {
            aR[0][oi] += u0r * wra[oi] - u0i * wia[oi];
            aI[0][oi] += u0r * wia[oi] + u0i * wra[oi];
            aR[1][oi] += u1r * wra[oi] - u1i * wia[oi];
            aI[1][oi] += u1r * wia[oi] + u1i * wra[oi];
        }
    }
    float* YRp = ws + OFF_YR + (size_t)hx * 2048;
    float* YIp = ws + OFF_YI + (size_t)hx * 2048;
#pragma unroll
    for (int bi = 0; bi < 2; ++bi) {
        float4 vr = { aR[bi][0], aR[bi][1], aR[bi][2], aR[bi][3] };
        float4 vi = { aI[bi][0], aI[bi][1], aI[bi][2], aI[bi][3] };
        *(float4*)&YRp[(b0 + bi) * 64 + o0] = vr;
        *(float4*)&YIp[(b0 + bi) * 64 + o0] = vi;
    }
}

// ---------------- iDFT via MFMA: out[o][t] = Acoef[o][kap] * B[kap][t] ------
// grid 256 = (b,h). 512 threads, 8 waves; wave owns 8 n-tiles (128 t).
__global__ __launch_bounds__(512, 2) void k_idft(const float* __restrict__ ws,
                                                 float* __restrict__ out) {
    __shared__ float Acoef[64 * 132];   // [o][kap], row stride 132 (2-way free)
    int bh = blockIdx.x;
    int b = bh >> 3, h = bh & 7;
    int tid = threadIdx.x;
    int lane = tid & 63, wv = tid >> 6;
    const float S0 = 3.7252902984619140625e-09f;   // 1/2^28
    const float* YRp = ws + OFF_YR;
    const float* YIp = ws + OFF_YI;
    const unsigned short* BIH = (const unsigned short*)ws + 262144;
    const unsigned short* BIL = (const unsigned short*)ws + 393216;

    for (int i = tid; i < 4096; i += 512) {
        int m = i >> 6, o = i & 63;
        size_t src = ((size_t)h * 64 + m) * 2048 + (size_t)b * 64 + o;
        float sca = (m == 0 ? 1.f : 2.f) * S0;
        Acoef[o * 132 + m] = YRp[src] * sca;
        Acoef[o * 132 + 64 + m] = YIp[src] * sca;
    }
    __syncthreads();

    // persistent A fragments: [mt][ks], split hi/lo
    bf16x8 ah[4][4], al[4][4];
#pragma unroll
    for (int mt = 0; mt < 4; ++mt)
#pragma unroll
        for (int ks = 0; ks < 4; ++ks) {
            int o = mt * 16 + (lane & 15);
            int kap0 = ks * 32 + (lane >> 4) * 8;
            float4 p0 = *(const float4*)&Acoef[o * 132 + kap0];
            float4 p1 = *(const float4*)&Acoef[o * 132 + kap0 + 4];
            float f[8] = { p0.x, p0.y, p0.z, p0.w, p1.x, p1.y, p1.z, p1.w };
            make_hilo8(f, ah[mt][ks], al[mt][ks]);
        }

    float* outp = out + ((size_t)b * 8 + h) * 65536;
#pragma unroll 2
    for (int ntl = 0; ntl < 8; ++ntl) {
        int nt = wv * 8 + ntl;
        f32x4 acc[4];
#pragma unroll
        for (int mt = 0; mt < 4; ++mt) acc[mt] = (f32x4){0.f, 0.f, 0.f, 0.f};
#pragma unroll
        for (int ks = 0; ks < 4; ++ks) {
            size_t off = (((size_t)nt * 4 + ks) * 64 + lane) * 8;
            bf16x8 bh = *(const bf16x8*)(BIH + off);
            bf16x8 bl = *(const bf16x8*)(BIL + off);
#pragma unroll
            for (int mt = 0; mt < 4; ++mt) {
                acc[mt] = __builtin_amdgcn_mfma_f32_16x16x32_bf16(ah[mt][ks], bh, acc[mt], 0, 0, 0);
                acc[mt] = __builtin_amdgcn_mfma_f32_16x16x32_bf16(ah[mt][ks], bl, acc[mt], 0, 0, 0);
                acc[mt] = __builtin_amdgcn_mfma_f32_16x16x32_bf16(al[mt][ks], bh, acc[mt], 0, 0, 0);
            }
        }
        int t = nt * 16 + (lane & 15);
#pragma unroll
        for (int mt = 0; mt < 4; ++mt) {
            int o0 = mt * 16 + (lane >> 4) * 4;
#pragma unroll
            for (int r = 0; r < 4; ++r)
                outp[(size_t)(o0 + r) * 1024 + t] = acc[mt][r];
        }
    }
}

extern "C" void kernel_launch(void* const* d_in, const int* in_sizes, int n_in,
                              void* d_out, int out_size, void* d_ws, size_t ws_size,
                              hipStream_t stream) {
    const float* q = (const float*)d_in[0];
    const float* k = (const float*)d_in[1];
    const float* wr = (const float*)d_in[4];
    const float* wi = (const float*)d_in[5];
    float* out = (float*)d_out;
    float* ws = (float*)d_ws;   // needs 51.4 MB

    k_tables<<<512, 256, 0, stream>>>((unsigned short*)d_ws);
    k_wt<<<512, 256, 0, stream>>>(wr, wi, ws);
    k_dft<<<512, 256, 0, stream>>>(q, k, ws);
    k_attn<<<256, 256, 0, stream>>>(ws);
    k_uw<<<512, 256, 0, stream>>>(ws);
    k_idft<<<256, 512, 0, stream>>>(ws, out);
}

// Round 3
// 309.502 us; speedup vs baseline: 2.3924x; 1.1022x over previous
//
#include <hip/hip_runtime.h>
#include <math.h>

// FourierCrossAttention, MI355X. Round 3: barrier-free MFMA DFT, MFMA attn/uw.
// B=32 H=8 E=64 M=64 O=64 L=1024.
//
// ws layout:
//   bytes [0, 1MB): bf16 twiddle tables in MFMA B-fragment layout (hi/lo)
//   floats from 262144: as before.
#define OFF_WTR   262144u   // wT[h][x][e][o]  2097152
#define OFF_WTI   2359296u
#define OFF_XQR   4456448u  // Xq [b][h][e][m] 1048576
#define OFF_XQI   5505024u
#define OFF_XKR   6553600u
#define OFF_XKI   7602176u
#define OFF_UR    8650752u  // u  [h][x][b][e] 1048576
#define OFF_UI    9699328u
#define OFF_YR    10747904u // xqkvw [h][x][b][o] 1048576
#define OFF_YI    11796480u

#define PI_F 3.14159265358979323846f

typedef __attribute__((ext_vector_type(8))) short bf16x8;
typedef __attribute__((ext_vector_type(4))) float f32x4;

__device__ inline unsigned short f2bf(float f) {
    unsigned u = __float_as_uint(f);
    unsigned r = u + 0x7FFFu + ((u >> 16) & 1u);
    return (unsigned short)(r >> 16);
}
__device__ inline float bf2f(unsigned short h) {
    return __uint_as_float(((unsigned)h) << 16);
}
__device__ inline void make_hilo8(const float* s, bf16x8& h, bf16x8& l) {
#pragma unroll
    for (int j = 0; j < 8; ++j) {
        unsigned short hb = f2bf(s[j]);
        h[j] = (short)hb;
        l[j] = (short)f2bf(s[j] - bf2f(hb));
    }
}
__device__ inline bf16x8 neg8(bf16x8 v) {
    bf16x8 r;
#pragma unroll
    for (int j = 0; j < 8; ++j) r[j] = (short)(((unsigned short)v[j]) ^ 0x8000u);
    return r;
}
__device__ inline float twval(int m, int t, bool neg_sin) {
    int r = (m * t) & 1023;
    float ang = (float)r * (2.0f * PI_F / 1024.0f);
    float s, c;
    sincosf(ang, &s, &c);
    return neg_sin ? -s : c;
}

// 3-pass split-bf16 MFMA: acc += (Ah+Al)*(Bh+Bl) approx
#define MFMA3(AH, AL, BH, BL, ACC)                                          \
    ACC = __builtin_amdgcn_mfma_f32_16x16x32_bf16(AH, BH, ACC, 0, 0, 0);    \
    ACC = __builtin_amdgcn_mfma_f32_16x16x32_bf16(AH, BL, ACC, 0, 0, 0);    \
    ACC = __builtin_amdgcn_mfma_f32_16x16x32_bf16(AL, BH, ACC, 0, 0, 0);

// ---------------- twiddle tables in MFMA B-fragment layout, split hi/lo -----
__global__ void k_tables(unsigned short* __restrict__ tab) {
    int idx = blockIdx.x * 256 + threadIdx.x;   // 131072 entries each table
    {
        int j = idx & 7, lane = (idx >> 3) & 63, nt = (idx >> 9) & 7, kt = idx >> 12;
        int k = kt * 32 + ((lane >> 4) << 3) + j;       // t (K dim)
        int n = nt * 16 + (lane & 15);                  // col in [0,128)
        float v = twval(n & 63, k, n >= 64);
        unsigned short hb = f2bf(v);
        tab[idx] = hb;
        tab[131072 + idx] = f2bf(v - bf2f(hb));
    }
    {
        int j = idx & 7, lane = (idx >> 3) & 63, ks = (idx >> 9) & 3, nt = idx >> 11;
        int kap = ks * 32 + ((lane >> 4) << 3) + j;     // kappa in [0,128)
        int t = nt * 16 + (lane & 15);
        float v = twval(kap & 63, t, kap >= 64);
        unsigned short hb = f2bf(v);
        tab[262144 + idx] = hb;
        tab[393216 + idx] = f2bf(v - bf2f(hb));
    }
}

// ---------------- transpose weights [h][e][o][x] -> [h][x][e][o] ------------
__global__ __launch_bounds__(256) void k_wt(const float* __restrict__ wr,
                                            const float* __restrict__ wi,
                                            float* __restrict__ ws) {
    __shared__ float tile[64 * 65];
    int he = blockIdx.x;            // h*64+e
    int h = he >> 6, e = he & 63;
    const float* srcs[2] = { wr + (size_t)he * 4096, wi + (size_t)he * 4096 };
    float* dsts[2] = { ws + OFF_WTR, ws + OFF_WTI };
    for (int p = 0; p < 2; ++p) {
        __syncthreads();
        {
            int x = threadIdx.x & 63, orow = threadIdx.x >> 6;
            for (int i = 0; i < 16; ++i) {
                int o = orow * 16 + i;
                tile[o * 65 + x] = srcs[p][o * 64 + x];
            }
        }
        __syncthreads();
        {
            int o = threadIdx.x & 63, xrow = threadIdx.x >> 6;
            for (int i = 0; i < 16; ++i) {
                int x = xrow * 16 + i;
                dsts[p][(((size_t)h * 64 + x) * 64 + e) * 64 + o] = tile[o * 65 + x];
            }
        }
    }
}

// ---------------- DFT via MFMA, barrier-free K-loop -------------------------
// grid 512: src*256 + bh. 512 threads, 8 waves = 2 khalf x 2 mhalf x 2 nhalf.
// A-frags loaded directly from global (lane&15 -> e contiguous = 64B segs).
__global__ __launch_bounds__(512, 4) void k_dft(const float* __restrict__ q,
                                                const float* __restrict__ kk,
                                                float* __restrict__ ws) {
    int blk = blockIdx.x;
    int src = blk >> 8;
    int bhi = blk & 255;
    int b = bhi >> 3, h = bhi & 7;
    const float* A = src ? kk : q;
    const unsigned short* BDH = (const unsigned short*)ws;
    const unsigned short* BDL = BDH + 131072;

    int tid = threadIdx.x;
    int lane = tid & 63, wv = tid >> 6;
    int kh = wv & 1, mh = (wv >> 1) & 1, nh = wv >> 2;

    f32x4 acc[2][4];
#pragma unroll
    for (int a = 0; a < 2; ++a)
#pragma unroll
        for (int c = 0; c < 4; ++c) acc[a][c] = (f32x4){0.f, 0.f, 0.f, 0.f};

    for (int kc = 0; kc < 8; ++kc) {
        int tbase = kh * 512 + kc * 64;
        bf16x8 ah[2][2], al[2][2];
#pragma unroll
        for (int mt = 0; mt < 2; ++mt) {
            int e = mh * 32 + mt * 16 + (lane & 15);
#pragma unroll
            for (int k2 = 0; k2 < 2; ++k2) {
                int t0 = tbase + k2 * 32 + (lane >> 4) * 8;
                float f[8];
#pragma unroll
                for (int j = 0; j < 8; ++j)
                    f[j] = A[(((size_t)b * 1024 + t0 + j) * 8 + h) * 64 + e];
                make_hilo8(f, ah[mt][k2], al[mt][k2]);
            }
        }
#pragma unroll
        for (int k2 = 0; k2 < 2; ++k2) {
            int ktile = kh * 16 + kc * 2 + k2;
#pragma unroll
            for (int ntl = 0; ntl < 4; ++ntl) {
                int nt = nh * 4 + ntl;
                size_t off = (((size_t)ktile * 8 + nt) * 64 + lane) * 8;
                bf16x8 tbh = *(const bf16x8*)(BDH + off);
                bf16x8 tbl = *(const bf16x8*)(BDL + off);
#pragma unroll
                for (int mt = 0; mt < 2; ++mt) {
                    MFMA3(ah[mt][k2], al[mt][k2], tbh, tbl, acc[mt][ntl]);
                }
            }
        }
    }

    // khalf reduction through LDS (conflict-free [reg][lane] layout)
    __shared__ float red[8192];
    int pair = wv >> 1;   // mh + 2*nh
    if (kh == 1) {
#pragma unroll
        for (int mt = 0; mt < 2; ++mt)
#pragma unroll
            for (int ntl = 0; ntl < 4; ++ntl)
#pragma unroll
                for (int r = 0; r < 4; ++r)
                    red[pair * 2048 + ((mt * 4 + ntl) * 4 + r) * 64 + lane] = acc[mt][ntl][r];
    }
    __syncthreads();
    if (kh == 0) {
        float* outR = ws + (src ? OFF_XKR : OFF_XQR) + (size_t)bhi * 4096;
        float* outI = ws + (src ? OFF_XKI : OFF_XQI) + (size_t)bhi * 4096;
#pragma unroll
        for (int mt = 0; mt < 2; ++mt)
#pragma unroll
            for (int ntl = 0; ntl < 4; ++ntl) {
#pragma unroll
                for (int r = 0; r < 4; ++r)
                    acc[mt][ntl][r] += red[pair * 2048 + ((mt * 4 + ntl) * 4 + r) * 64 + lane];
                int n = (nh * 4 + ntl) * 16 + (lane & 15);
                float* dst = (n < 64) ? (outR + n) : (outI + (n - 64));
                int erow0 = mh * 32 + mt * 16 + (lane >> 4) * 4;
#pragma unroll
                for (int r = 0; r < 4; ++r)
                    dst[(erow0 + r) * 64] = acc[mt][ntl][r];
            }
    }
}

// ---------------- attn: S = Xq^T Xk, tanh, u = S~ Xk^T, all MFMA ------------
// grid 256 = (b,h); 256 threads, 4 waves; wave owns 16 rows (x).
__global__ __launch_bounds__(256, 1) void k_attn(float* __restrict__ ws) {
    __shared__ float sKR[64 * 65], sKI[64 * 65];
    __shared__ float sQR[64 * 65], sQI[64 * 65];   // later reused for S~
    int bhi = blockIdx.x;
    int b = bhi >> 3, h = bhi & 7;
    int tid = threadIdx.x, lane = tid & 63, wv = tid >> 6;
    const float* XqR = ws + OFF_XQR + (size_t)bhi * 4096;
    const float* XqI = ws + OFF_XQI + (size_t)bhi * 4096;
    const float* XkR = ws + OFF_XKR + (size_t)bhi * 4096;
    const float* XkI = ws + OFF_XKI + (size_t)bhi * 4096;
    for (int i = tid; i < 4096; i += 256) {
        int e = i >> 6, m = i & 63;
        sQR[e * 65 + m] = XqR[i];
        sQI[e * 65 + m] = XqI[i];
        sKR[e * 65 + m] = XkR[i];
        sKI[e * 65 + m] = XkI[i];
    }
    __syncthreads();

    // ---- GEMM1 A-frags: A[m=x][k=e] = Xq[e][x]
    int x = wv * 16 + (lane & 15);
    bf16x8 aRh[2], aRl[2], aIh[2], aIl[2], aInh[2], aInl[2];
#pragma unroll
    for (int k2 = 0; k2 < 2; ++k2) {
        float fr[8], fi[8];
#pragma unroll
        for (int j = 0; j < 8; ++j) {
            int e = k2 * 32 + (lane >> 4) * 8 + j;
            fr[j] = sQR[e * 65 + x];
            fi[j] = sQI[e * 65 + x];
        }
        make_hilo8(fr, aRh[k2], aRl[k2]);
        make_hilo8(fi, aIh[k2], aIl[k2]);
        aInh[k2] = neg8(aIh[k2]);
        aInl[k2] = neg8(aIl[k2]);
    }
    __syncthreads();   // all Xq reads done before S~ overwrites sQ

    // ---- GEMM1: S[x][y], K=e
    f32x4 Sr[4], Si[4];
#pragma unroll
    for (int c = 0; c < 4; ++c) { Sr[c] = (f32x4){0.f,0.f,0.f,0.f}; Si[c] = (f32x4){0.f,0.f,0.f,0.f}; }
#pragma unroll
    for (int k2 = 0; k2 < 2; ++k2) {
#pragma unroll
        for (int nt = 0; nt < 4; ++nt) {
            float gr[8], gi[8];
            int y = nt * 16 + (lane & 15);
#pragma unroll
            for (int j = 0; j < 8; ++j) {
                int e = k2 * 32 + (lane >> 4) * 8 + j;
                gr[j] = sKR[e * 65 + y];
                gi[j] = sKI[e * 65 + y];
            }
            bf16x8 bRh, bRl, bIh, bIl;
            make_hilo8(gr, bRh, bRl);
            make_hilo8(gi, bIh, bIl);
            MFMA3(aRh[k2], aRl[k2], bRh, bRl, Sr[nt]);
            MFMA3(aInh[k2], aInl[k2], bIh, bIl, Sr[nt]);
            MFMA3(aRh[k2], aRl[k2], bIh, bIl, Si[nt]);
            MFMA3(aIh[k2], aIl[k2], bRh, bRl, Si[nt]);
        }
    }
#pragma unroll
    for (int nt = 0; nt < 4; ++nt)
#pragma unroll
        for (int r = 0; r < 4; ++r) {
            Sr[nt][r] = tanhf(Sr[nt][r]);
            Si[nt][r] = tanhf(Si[nt][r]);
        }
    // write S~ [x][y] stride 65 into sQ region
#pragma unroll
    for (int nt = 0; nt < 4; ++nt) {
        int y = nt * 16 + (lane & 15);
        int xr0 = wv * 16 + (lane >> 4) * 4;
#pragma unroll
        for (int r = 0; r < 4; ++r) {
            sQR[(xr0 + r) * 65 + y] = Sr[nt][r];
            sQI[(xr0 + r) * 65 + y] = Si[nt][r];
        }
    }
    __syncthreads();

    // ---- GEMM2 A-frags: A[m=x][k=y] = S~[x][y]
    bf16x8 cRh[2], cRl[2], cIh[2], cIl[2], cInh[2], cInl[2];
#pragma unroll
    for (int k2 = 0; k2 < 2; ++k2) {
        float fr[8], fi[8];
#pragma unroll
        for (int j = 0; j < 8; ++j) {
            int y = k2 * 32 + (lane >> 4) * 8 + j;
            fr[j] = sQR[x * 65 + y];
            fi[j] = sQI[x * 65 + y];
        }
        make_hilo8(fr, cRh[k2], cRl[k2]);
        make_hilo8(fi, cIh[k2], cIl[k2]);
        cInh[k2] = neg8(cIh[k2]);
        cInl[k2] = neg8(cIl[k2]);
    }

    // ---- GEMM2: u[x][e] = sum_y S~[x][y] * Xk[e][y]  (B[k=y][n=e] = XkT)
    f32x4 Ur[4], Ui[4];
#pragma unroll
    for (int c = 0; c < 4; ++c) { Ur[c] = (f32x4){0.f,0.f,0.f,0.f}; Ui[c] = (f32x4){0.f,0.f,0.f,0.f}; }
#pragma unroll
    for (int k2 = 0; k2 < 2; ++k2) {
#pragma unroll
        for (int nt = 0; nt < 4; ++nt) {
            float gr[8], gi[8];
            int e = nt * 16 + (lane & 15);
#pragma unroll
            for (int j = 0; j < 8; ++j) {
                int y = k2 * 32 + (lane >> 4) * 8 + j;
                gr[j] = sKR[e * 65 + y];
                gi[j] = sKI[e * 65 + y];
            }
            bf16x8 bRh, bRl, bIh, bIl;
            make_hilo8(gr, bRh, bRl);
            make_hilo8(gi, bIh, bIl);
            MFMA3(cRh[k2], cRl[k2], bRh, bRl, Ur[nt]);
            MFMA3(cInh[k2], cInl[k2], bIh, bIl, Ur[nt]);
            MFMA3(cRh[k2], cRl[k2], bIh, bIl, Ui[nt]);
            MFMA3(cIh[k2], cIl[k2], bRh, bRl, Ui[nt]);
        }
    }
    // write u: [h][x][b][e]
    float* uRp = ws + OFF_UR;
    float* uIp = ws + OFF_UI;
#pragma unroll
    for (int nt = 0; nt < 4; ++nt) {
        int e = nt * 16 + (lane & 15);
        int xr0 = wv * 16 + (lane >> 4) * 4;
#pragma unroll
        for (int r = 0; r < 4; ++r) {
            size_t base = (((size_t)h * 64 + xr0 + r) * 32 + b) * 64 + e;
            uRp[base] = Ur[nt][r];
            uIp[base] = Ui[nt][r];
        }
    }
}

// ---------------- uw: Y[b][o] = sum_e u[b][e]*w[e][o]  per (h,x), MFMA ------
// grid 512 = hx; 256 threads, 4 waves; wave owns one o-tile (nt = wv).
__global__ __launch_bounds__(256, 2) void k_uw(float* __restrict__ ws) {
    int hx = blockIdx.x;
    int tid = threadIdx.x, lane = tid & 63, wv = tid >> 6;
    const float* uRp = ws + OFF_UR + (size_t)hx * 2048;
    const float* uIp = ws + OFF_UI + (size_t)hx * 2048;
    const float* wRp = ws + OFF_WTR + (size_t)hx * 4096;
    const float* wIp = ws + OFF_WTI + (size_t)hx * 4096;

    // A-frags: A[m=b][k=e] = u[b][e] (contiguous)
    bf16x8 aRh[2][2], aRl[2][2], aIh[2][2], aIl[2][2], aInh[2][2], aInl[2][2];
#pragma unroll
    for (int mt = 0; mt < 2; ++mt) {
        int bb = mt * 16 + (lane & 15);
#pragma unroll
        for (int k2 = 0; k2 < 2; ++k2) {
            int e0 = k2 * 32 + (lane >> 4) * 8;
            float fr[8], fi[8];
#pragma unroll
            for (int j = 0; j < 8; ++j) {
                fr[j] = uRp[bb * 64 + e0 + j];
                fi[j] = uIp[bb * 64 + e0 + j];
            }
            make_hilo8(fr, aRh[mt][k2], aRl[mt][k2]);
            make_hilo8(fi, aIh[mt][k2], aIl[mt][k2]);
            aInh[mt][k2] = neg8(aIh[mt][k2]);
            aInl[mt][k2] = neg8(aIl[mt][k2]);
        }
    }

    f32x4 Yr[2], Yi[2];
#pragma unroll
    for (int mt = 0; mt < 2; ++mt) { Yr[mt] = (f32x4){0.f,0.f,0.f,0.f}; Yi[mt] = (f32x4){0.f,0.f,0.f,0.f}; }
    int o = wv * 16 + (lane & 15);
#pragma unroll
    for (int k2 = 0; k2 < 2; ++k2) {
        float gr[8], gi[8];
#pragma unroll
        for (int j = 0; j < 8; ++j) {
            int e = k2 * 32 + (lane >> 4) * 8 + j;
            gr[j] = wRp[e * 64 + o];
            gi[j] = wIp[e * 64 + o];
        }
        bf16x8 bRh, bRl, bIh, bIl;
        make_hilo8(gr, bRh, bRl);
        make_hilo8(gi, bIh, bIl);
#pragma unroll
        for (int mt = 0; mt < 2; ++mt) {
            MFMA3(aRh[mt][k2], aRl[mt][k2], bRh, bRl, Yr[mt]);
            MFMA3(aInh[mt][k2], aInl[mt][k2], bIh, bIl, Yr[mt]);
            MFMA3(aRh[mt][k2], aRl[mt][k2], bIh, bIl, Yi[mt]);
            MFMA3(aIh[mt][k2], aIl[mt][k2], bRh, bRl, Yi[mt]);
        }
    }
    float* YRp = ws + OFF_YR + (size_t)hx * 2048;
    float* YIp = ws + OFF_YI + (size_t)hx * 2048;
#pragma unroll
    for (int mt = 0; mt < 2; ++mt) {
#pragma unroll
        for (int r = 0; r < 4; ++r) {
            int bb = mt * 16 + (lane >> 4) * 4 + r;
            YRp[bb * 64 + o] = Yr[mt][r];
            YIp[bb * 64 + o] = Yi[mt][r];
        }
    }
}

// ---------------- iDFT via MFMA: out[o][t] = Acoef[o][kap] * B[kap][t] ------
// grid 512 = (b,h) x nhalf. 512 threads, 8 waves; wave owns 4 n-tiles (64 t).
__global__ __launch_bounds__(512, 2) void k_idft(const float* __restrict__ ws,
                                                 float* __restrict__ out) {
    __shared__ float Acoef[64 * 132];   // [o][kap], row stride 132
    int blk = blockIdx.x;
    int bhi = blk >> 1, nhf = blk & 1;
    int b = bhi >> 3, h = bhi & 7;
    int tid = threadIdx.x;
    int lane = tid & 63, wv = tid >> 6;
    const float S0 = 3.7252902984619140625e-09f;   // 1/2^28
    const float* YRp = ws + OFF_YR;
    const float* YIp = ws + OFF_YI;
    const unsigned short* BIH = (const unsigned short*)ws + 262144;
    const unsigned short* BIL = (const unsigned short*)ws + 393216;

    for (int i = tid; i < 4096; i += 512) {
        int m = i >> 6, o = i & 63;
        size_t src = ((size_t)h * 64 + m) * 2048 + (size_t)b * 64 + o;
        float sca = (m == 0 ? 1.f : 2.f) * S0;
        Acoef[o * 132 + m] = YRp[src] * sca;
        Acoef[o * 132 + 64 + m] = YIp[src] * sca;
    }
    __syncthreads();

    bf16x8 ah[4][4], al[4][4];
#pragma unroll
    for (int mt = 0; mt < 4; ++mt)
#pragma unroll
        for (int ks = 0; ks < 4; ++ks) {
            int o = mt * 16 + (lane & 15);
            int kap0 = ks * 32 + (lane >> 4) * 8;
            float4 p0 = *(const float4*)&Acoef[o * 132 + kap0];
            float4 p1 = *(const float4*)&Acoef[o * 132 + kap0 + 4];
            float f[8] = { p0.x, p0.y, p0.z, p0.w, p1.x, p1.y, p1.z, p1.w };
            make_hilo8(f, ah[mt][ks], al[mt][ks]);
        }

    float* outp = out + ((size_t)b * 8 + h) * 65536;
#pragma unroll 2
    for (int ntl = 0; ntl < 4; ++ntl) {
        int nt = nhf * 32 + wv * 4 + ntl;
        f32x4 acc[4];
#pragma unroll
        for (int mt = 0; mt < 4; ++mt) acc[mt] = (f32x4){0.f, 0.f, 0.f, 0.f};
#pragma unroll
        for (int ks = 0; ks < 4; ++ks) {
            size_t off = (((size_t)nt * 4 + ks) * 64 + lane) * 8;
            bf16x8 tbh = *(const bf16x8*)(BIH + off);
            bf16x8 tbl = *(const bf16x8*)(BIL + off);
#pragma unroll
            for (int mt = 0; mt < 4; ++mt) {
                MFMA3(ah[mt][ks], al[mt][ks], tbh, tbl, acc[mt]);
            }
        }
        int t = nt * 16 + (lane & 15);
#pragma unroll
        for (int mt = 0; mt < 4; ++mt) {
            int o0 = mt * 16 + (lane >> 4) * 4;
#pragma unroll
            for (int r = 0; r < 4; ++r)
                outp[(size_t)(o0 + r) * 1024 + t] = acc[mt][r];
        }
    }
}

extern "C" void kernel_launch(void* const* d_in, const int* in_sizes, int n_in,
                              void* d_out, int out_size, void* d_ws, size_t ws_size,
                              hipStream_t stream) {
    const float* q = (const float*)d_in[0];
    const float* k = (const float*)d_in[1];
    const float* wr = (const float*)d_in[4];
    const float* wi = (const float*)d_in[5];
    float* out = (float*)d_out;
    float* ws = (float*)d_ws;   // needs 51.4 MB

    k_tables<<<512, 256, 0, stream>>>((unsigned short*)d_ws);
    k_wt<<<512, 256, 0, stream>>>(wr, wi, ws);
    k_dft<<<512, 512, 0, stream>>>(q, k, ws);
    k_attn<<<256, 256, 0, stream>>>(ws);
    k_uw<<<512, 256, 0, stream>>>(ws);
    k_idft<<<512, 512, 0, stream>>>(ws, out);
}